// Round 9
// baseline (4603.349 us; speedup 1.0000x reference)
//
#include <hip/hip_runtime.h>
#include <hip/hip_bf16.h>
#include <cstdint>
#include <cstddef>

// Problem constants (fixed by reference)
#define B_    8
#define T_    256
#define D_    512
#define W_    32
#define L_    4
#define A_    6
#define H_    8
#define DH_   64
#define DHP   65                 // padded LDS row (attn bank-conflict fix, R5)
#define NWIN  (B_*T_)            // 2048 windows
#define NTOK  (NWIN*W_)          // 65536 token rows

typedef __hip_bfloat16 bf16;
using bf16x8 = __attribute__((ext_vector_type(8))) short;  // MFMA A/B frag (4 VGPR)
using f32x4  = __attribute__((ext_vector_type(4))) float;  // MFMA C/D frag

// ---- memory plan (bytes): bf16-only residual stream ----------------------
#define XB_BYTES  ((size_t)NTOK * D_ * 2)     // 64 MiB bf16 residual master
#define WQ_ELEMS  ((size_t)L_ * 3*D_*D_)
#define WO_ELEMS  ((size_t)L_ * D_*D_)
#define W1_ELEMS  ((size_t)L_ * 4*D_*D_)
#define W2_ELEMS  ((size_t)L_ * 4*D_*D_)
#define WB_BYTES  ((WQ_ELEMS + WO_ELEMS + W1_ELEMS + W2_ELEMS) * 2)
#define SCR_BYTES ((size_t)NTOK * 2048 * 2)   // qkv(1536)+ctx(512) / h(2048)
#define TOTAL_BYTES (XB_BYTES + WB_BYTES + SCR_BYTES)

static char* g_fallback = nullptr;
__attribute__((constructor)) static void alloc_fallback() {
    (void)hipMalloc((void**)&g_fallback, TOTAL_BYTES);
}

// ---- async global->LDS (16B per lane; LDS dest = wave base + lane*16) -----
typedef __attribute__((address_space(3))) uint8_t* as3p;
typedef const __attribute__((address_space(1))) uint8_t* as1p;
__device__ __forceinline__ void gload_lds16(const void* g, void* l) {
    __builtin_amdgcn_global_load_lds((as1p)(const uint8_t*)g,
                                     (as3p)(uint32_t)(uintptr_t)l, 16, 0, 0);
}

__device__ __forceinline__ float bf2f(short s) {
    return __uint_as_float(((uint32_t)(uint16_t)s) << 16);
}

// ---------------------------------------------------------------------------
// weight convert fp32 -> bf16 (4 elems/thread)
// ---------------------------------------------------------------------------
__global__ __launch_bounds__(256) void cvt_kernel(
    const float* __restrict__ w, bf16* __restrict__ o, int n4)
{
    int i = blockIdx.x * 256 + threadIdx.x;
    if (i >= n4) return;
    float4 f = ((const float4*)w)[i];
    bf16* d = o + (size_t)i * 4;
    d[0] = __float2bfloat16(f.x);
    d[1] = __float2bfloat16(f.y);
    d[2] = __float2bfloat16(f.z);
    d[3] = __float2bfloat16(f.w);
}

// ---------------------------------------------------------------------------
// build_x: xb[n*32+w,:] = bf16(feats[b, max(t+w-31,0),:] + pos[w,:])
// ---------------------------------------------------------------------------
__global__ __launch_bounds__(256) void build_x_kernel(
    const float* __restrict__ feats,
    const float* __restrict__ pos,
    bf16* __restrict__ xb)
{
    int gid   = blockIdx.x * 256 + threadIdx.x;   // over NTOK * (D/4)
    int token = gid >> 7;
    int c4    = (gid & 127) * 4;
    int w     = token & (W_-1);
    int n     = token >> 5;
    int t     = n & (T_-1);
    int b     = n >> 8;
    int frame = t + w - (W_-1); if (frame < 0) frame = 0;
    const float4 f = *(const float4*)(feats + ((size_t)(b*T_ + frame)*D_ + c4));
    const float4 p = *(const float4*)(pos   + ((size_t)w*D_ + c4));
    bf16* d = xb + (size_t)token*D_ + c4;
    d[0] = __float2bfloat16(f.x + p.x);
    d[1] = __float2bfloat16(f.y + p.y);
    d[2] = __float2bfloat16(f.z + p.z);
    d[3] = __float2bfloat16(f.w + p.w);
}

// ---------------------------------------------------------------------------
// bf16 MFMA GEMM (no resid): Cb = bf16(A(MxK) @ Bt(NxK)^T + bias [relu])
// 128x128 tile, BK=64 (R9: halves barrier-drain count vs BK=32; LDS 32 KB),
// 4 waves, wave 64x64 (4x4 of 16x16x32 MFMA, 2 k-halves per K-step).
// 1-D grid + XCD remap (R7: same-A-stripe blocks share one XCD L2).
// K % 64 == 0 (used with K=512 only).
// ---------------------------------------------------------------------------
template<bool RELU>
__global__ __launch_bounds__(256) void gemm_bf16(
    const bf16* __restrict__ A,
    const bf16* __restrict__ Bt,
    const float* __restrict__ bias,
    bf16* __restrict__ Cb,
    int M, int N, int K)
{
    __shared__ bf16 As[128*64];   // 16 KB, [row][k], 128-B rows
    __shared__ bf16 Bs[128*64];

    const int tid  = threadIdx.x;
    const int lane = tid & 63;
    const int wv   = tid >> 6;

    // XCD-aware block remap (gridM % 8 == 0)
    const int gridN = N >> 7;
    const int bid   = blockIdx.x;
    const int q_    = bid >> 3;
    const int n0    = (q_ % gridN) << 7;
    const int m0    = (((q_ / gridN) * 8) + (bid & 7)) << 7;

    const int wm   = (wv >> 1) * 64;
    const int wn   = (wv & 1) * 64;

    f32x4 acc[4][4] = {};

    // staging: round j (0..3): row = j*32 + (tid>>3), 16-B chunk (tid&7)
    const int   srow = tid >> 3;          // 0..31
    const int   skof = (tid & 7) * 8;     // elems
    const bf16* gA = A  + (size_t)(m0 + srow) * K + skof;
    const bf16* gB = Bt + (size_t)(n0 + srow) * K + skof;
    char* lAs = (char*)As;
    char* lBs = (char*)Bs;
    const int ld0 = tid * 16;             // + j*4096

    const int fr = lane & 15;
    const int fq = (lane >> 4) * 16;      // bytes within a 64-B k-half

    for (int k0 = 0; k0 < K; k0 += 64) {
#pragma unroll
        for (int j = 0; j < 4; ++j) {
            gload_lds16(gA + (size_t)(j*32) * K + k0, lAs + j*4096 + ld0);
            gload_lds16(gB + (size_t)(j*32) * K + k0, lBs + j*4096 + ld0);
        }
        __syncthreads();   // drains vmcnt (DMA) before reads

#pragma unroll
        for (int h = 0; h < 2; ++h) {
            bf16x8 av[4], bv[4];
#pragma unroll
            for (int i = 0; i < 4; ++i) {
                av[i] = *(const bf16x8*)(lAs + (wm + i*16 + fr)*128 + h*64 + fq);
                bv[i] = *(const bf16x8*)(lBs + (wn + i*16 + fr)*128 + h*64 + fq);
            }
#pragma unroll
            for (int i = 0; i < 4; ++i)
#pragma unroll
                for (int j = 0; j < 4; ++j)
                    acc[i][j] = __builtin_amdgcn_mfma_f32_16x16x32_bf16(
                        av[i], bv[j], acc[i][j], 0, 0, 0);
        }
        __syncthreads();
    }

    // epilogue: C/D layout col=lane&15, row=(lane>>4)*4+reg
    const int er = (lane >> 4) * 4;
    const int ec = lane & 15;
#pragma unroll
    for (int i = 0; i < 4; ++i) {
#pragma unroll
        for (int j = 0; j < 4; ++j) {
            const int ncol = n0 + wn + j*16 + ec;
            const float bv_ = bias[ncol];
#pragma unroll
            for (int r = 0; r < 4; ++r) {
                const int mrow = m0 + wm + i*16 + er + r;
                float v = acc[i][j][r] + bv_;
                if (RELU) v = fmaxf(v, 0.f);
                Cb[(size_t)mrow * N + ncol] = __float2bfloat16(v);
            }
        }
    }
}

// ---------------------------------------------------------------------------
// Fused residual GEMM + LayerNorm (R9: 64 rows x 512 cols, 512 threads):
//   y = xres + A @ Bt^T + bias;  xout = LN(y)*g + b     (N fixed = 512)
// 8 waves: wave (rh=wv>>2, cg=wv&3) covers rows rh*32..+32, cols cg*128..+128.
// Halves B-staging per FLOP vs R8's 32-row tile (B panel 32 KB/K-step now
// amortized over 2x rows). LN: shfl over 16 col-lanes -> red[cg][64][2] ->
// cross-wave sum. In-place xres==xout safe: block owns its 64 rows.
// ---------------------------------------------------------------------------
__global__ __launch_bounds__(512) void gemm_ln(
    const bf16* __restrict__ A,     // (M x K)
    const bf16* __restrict__ Bt,    // (512 x K)
    const float* __restrict__ bias, // (512)
    const bf16* xres,               // (M x 512), aliases xout
    bf16* xout,
    const float* __restrict__ g,
    const float* __restrict__ b,
    int K)
{
    __shared__ bf16 As[64*32];      // 4 KB, 64-B rows
    __shared__ bf16 Bs[512*32];     // 32 KB, 64-B rows
    __shared__ float red[4][64][2]; // 2 KB

    const int tid  = threadIdx.x;   // 0..511
    const int lane = tid & 63;
    const int wv   = tid >> 6;      // 0..7
    const int rh   = wv >> 2;       // row half
    const int cg   = wv & 3;        // col group
    const int m0   = blockIdx.x * 64;

    f32x4 acc[2][8] = {};

    const bf16* gaA = A + (size_t)(m0 + (tid >> 2)) * K + (tid & 3) * 8; // tid<256
    char* lAs = (char*)As;
    char* lBs = (char*)Bs;

    const int fr = lane & 15;
    const int fq = (lane >> 4) * 16;
    const int wr = rh * 32;
    const int wc = cg * 128;

    for (int k0 = 0; k0 < K; k0 += 32) {
        if (tid < 256) gload_lds16(gaA + k0, lAs + tid*16);
#pragma unroll
        for (int j = 0; j < 4; ++j) {
            const bf16* gb = Bt + (size_t)(j*128 + (tid >> 2)) * K + k0 + (tid & 3) * 8;
            gload_lds16(gb, lBs + j*8192 + tid*16);
        }
        __syncthreads();

        bf16x8 av[2], bv[8];
#pragma unroll
        for (int i = 0; i < 2; ++i)
            av[i] = *(const bf16x8*)(lAs + (wr + i*16 + fr)*64 + fq);
#pragma unroll
        for (int j = 0; j < 8; ++j)
            bv[j] = *(const bf16x8*)(lBs + (wc + j*16 + fr)*64 + fq);
#pragma unroll
        for (int i = 0; i < 2; ++i)
#pragma unroll
            for (int j = 0; j < 8; ++j)
                acc[i][j] = __builtin_amdgcn_mfma_f32_16x16x32_bf16(
                    av[i], bv[j], acc[i][j], 0, 0, 0);
        __syncthreads();
    }

    // ---- epilogue: v = acc + bias + resid; LN over the 512-wide row ----
    const int er = (lane >> 4) * 4;
    const int ec = lane & 15;

    float bias_j[8];
#pragma unroll
    for (int j = 0; j < 8; ++j) bias_j[j] = bias[wc + j*16 + ec];

#pragma unroll
    for (int i = 0; i < 2; ++i) {
#pragma unroll
        for (int r = 0; r < 4; ++r) {
            const int row = wr + i*16 + er + r;             // 0..63
            const bf16* xr = xres + (size_t)(m0 + row) * D_ + wc + ec;
            float s1 = 0.f, s2 = 0.f;
#pragma unroll
            for (int j = 0; j < 8; ++j) {
                float v = acc[i][j][r] + bias_j[j] + bf2f(*(const short*)(xr + j*16));
                acc[i][j][r] = v;
                s1 += v; s2 += v*v;
            }
#pragma unroll
            for (int mask = 1; mask < 16; mask <<= 1) {
                s1 += __shfl_xor(s1, mask, 64);
                s2 += __shfl_xor(s2, mask, 64);
            }
            if (ec == 0) { red[cg][row][0] = s1; red[cg][row][1] = s2; }
        }
    }
    __syncthreads();

#pragma unroll
    for (int i = 0; i < 2; ++i) {
#pragma unroll
        for (int r = 0; r < 4; ++r) {
            const int row = wr + i*16 + er + r;
            float t1 = red[0][row][0] + red[1][row][0] + red[2][row][0] + red[3][row][0];
            float t2 = red[0][row][1] + red[1][row][1] + red[2][row][1] + red[3][row][1];
            const float mu  = t1 * (1.f / D_);
            float var = t2 * (1.f / D_) - mu * mu;
            if (var < 0.f) var = 0.f;
            const float rs = rsqrtf(var + 1e-5f);
            bf16* xo = xout + (size_t)(m0 + row) * D_ + wc + ec;
#pragma unroll
            for (int j = 0; j < 8; ++j) {
                const int col = wc + j*16 + ec;
                float o = (acc[i][j][r] - mu) * rs * g[col] + b[col];
                xo[j*16] = __float2bfloat16(o);
            }
        }
    }
}

// ---------------------------------------------------------------------------
// Attention: block per (window, head); bf16 qkv in, bf16 ctx out; fp32 inside.
// LDS rows padded to DHP=65 floats (R5 bank-conflict fix).
// ---------------------------------------------------------------------------
__global__ __launch_bounds__(256) void attn_kernel(
    const bf16* __restrict__ qkv,
    bf16* __restrict__ ctx)
{
    const int n = blockIdx.x;
    const int h = blockIdx.y;
    __shared__ float q[W_][DHP];
    __shared__ float k[W_][DHP];
    __shared__ float v[W_][DHP];
    __shared__ float s[W_][W_ + 1];

    const int tid = threadIdx.x;
    {
        int r  = tid >> 3;
        int c0 = (tid & 7) * 8;
        const bf16* base = qkv + (size_t)(n*W_ + r) * (3*D_) + h*DH_ + c0;
        bf16x8 tq = *(const bf16x8*)(base);
        bf16x8 tk = *(const bf16x8*)(base + D_);
        bf16x8 tv = *(const bf16x8*)(base + 2*D_);
#pragma unroll
        for (int j = 0; j < 8; ++j) {
            q[r][c0 + j] = bf2f(tq[j]);
            k[r][c0 + j] = bf2f(tk[j]);
            v[r][c0 + j] = bf2f(tv[j]);
        }
    }
    __syncthreads();

    const int i = tid >> 3;
    {
        int j0 = (tid & 7) * 4;
#pragma unroll
        for (int jj = 0; jj < 4; ++jj) {
            int j = j0 + jj;
            float d = 0.f;
#pragma unroll
            for (int kk = 0; kk < DH_; ++kk) d += q[i][kk] * k[j][kk];
            s[i][j] = (j <= i) ? d * 0.125f : -1e30f;
        }
    }
    __syncthreads();

    if (tid < W_) {
        float mx = -1e30f;
#pragma unroll
        for (int j = 0; j < W_; ++j) mx = fmaxf(mx, s[tid][j]);
        float sum = 0.f;
#pragma unroll
        for (int j = 0; j < W_; ++j) { float e = __expf(s[tid][j] - mx); s[tid][j] = e; sum += e; }
        float inv = 1.f / sum;
#pragma unroll
        for (int j = 0; j < W_; ++j) s[tid][j] *= inv;
    }
    __syncthreads();

    {
        int d0 = (tid & 7) * 8;
        float o[8] = {0,0,0,0,0,0,0,0};
#pragma unroll
        for (int j = 0; j < W_; ++j) {
            float a = s[i][j];
#pragma unroll
            for (int dd = 0; dd < 8; ++dd) o[dd] += a * v[j][d0 + dd];
        }
        bf16* dst = ctx + (size_t)(n*W_ + i) * D_ + h*DH_ + d0;
#pragma unroll
        for (int dd = 0; dd < 8; ++dd) dst[dd] = __float2bfloat16(o[dd]);
    }
}

// ---------------------------------------------------------------------------
// Head: token = xb[n*32+31,:] bf16; logits (NWIN,6) then values (NWIN)
// ---------------------------------------------------------------------------
__global__ __launch_bounds__(64) void head_kernel(
    const bf16* __restrict__ xb,
    const float* __restrict__ Wp, const float* __restrict__ bp,
    const float* __restrict__ Wv, const float* __restrict__ bv,
    float* __restrict__ out)
{
    const int n    = blockIdx.x;
    const int lane = threadIdx.x;
    const bf16* row = xb + (size_t)(n*W_ + (W_-1)) * D_;
    float t[8];
#pragma unroll
    for (int j = 0; j < 8; ++j) t[j] = bf2f(*(const short*)(row + lane + j*64));

    for (int a = 0; a < A_ + 1; ++a) {
        const float* w = (a < A_) ? (Wp + (size_t)a * D_) : Wv;
        float d = 0.f;
#pragma unroll
        for (int j = 0; j < 8; ++j) d += t[j] * w[lane + j*64];
#pragma unroll
        for (int off = 32; off > 0; off >>= 1) d += __shfl_down(d, off);
        if (lane == 0) {
            if (a < A_) out[(size_t)n*A_ + a] = d + bp[a];
            else        out[(size_t)NWIN*A_ + n] = d + bv[0];
        }
    }
}

// ---------------------------------------------------------------------------
extern "C" void kernel_launch(void* const* d_in, const int* in_sizes, int n_in,
                              void* d_out, int out_size, void* d_ws, size_t ws_size,
                              hipStream_t stream) {
    const float* feats = (const float*)d_in[0];
    const float* pos   = (const float*)d_in[1];
    const float* Wqkv  = (const float*)d_in[2];
    const float* bqkv  = (const float*)d_in[3];
    const float* Wo    = (const float*)d_in[4];
    const float* bo    = (const float*)d_in[5];
    const float* ln1g  = (const float*)d_in[6];
    const float* ln1b  = (const float*)d_in[7];
    const float* W1    = (const float*)d_in[8];
    const float* b1    = (const float*)d_in[9];
    const float* W2    = (const float*)d_in[10];
    const float* b2    = (const float*)d_in[11];
    const float* ln2g  = (const float*)d_in[12];
    const float* ln2b  = (const float*)d_in[13];
    const float* Wp    = (const float*)d_in[14];
    const float* bp    = (const float*)d_in[15];
    const float* Wv    = (const float*)d_in[16];
    const float* bv    = (const float*)d_in[17];
    float* out = (float*)d_out;

    char* basep = (ws_size >= TOTAL_BYTES) ? (char*)d_ws : g_fallback;

    bf16*  xb   = (bf16*)basep;
    bf16*  wq_b = (bf16*)(basep + XB_BYTES);
    bf16*  wo_b = wq_b + WQ_ELEMS;
    bf16*  w1_b = wo_b + WO_ELEMS;
    bf16*  w2_b = w1_b + W1_ELEMS;
    bf16*  scr  = w2_b + W2_ELEMS;
    bf16*  qkv_s = scr;                            // (NTOK, 1536)
    bf16*  ctx_s = scr + (size_t)NTOK * (3*D_);    // (NTOK, 512)
    bf16*  h_s   = scr;                            // (NTOK, 2048) FFN phase

    cvt_kernel<<<(WQ_ELEMS/4 + 255)/256, 256, 0, stream>>>(Wqkv, wq_b, WQ_ELEMS/4);
    cvt_kernel<<<(WO_ELEMS/4 + 255)/256, 256, 0, stream>>>(Wo,   wo_b, WO_ELEMS/4);
    cvt_kernel<<<(W1_ELEMS/4 + 255)/256, 256, 0, stream>>>(W1,   w1_b, W1_ELEMS/4);
    cvt_kernel<<<(W2_ELEMS/4 + 255)/256, 256, 0, stream>>>(W2,   w2_b, W2_ELEMS/4);

    build_x_kernel<<<NTOK * (D_/4) / 256, 256, 0, stream>>>(feats, pos, xb);

    const int GM = NTOK / 128;   // 512 m-blocks (div by 8, XCD remap ok)

    for (int i = 0; i < L_; ++i) {
        const bf16*  wq_i = wq_b + (size_t)i * 3*D_*D_;
        const float* bq_i = bqkv + (size_t)i * 3*D_;
        const bf16*  wo_i = wo_b + (size_t)i * D_*D_;
        const float* bo_i = bo   + (size_t)i * D_;
        const bf16*  w1_i = w1_b + (size_t)i * 4*D_*D_;
        const float* b1_i = b1   + (size_t)i * 4*D_;
        const bf16*  w2_i = w2_b + (size_t)i * 4*D_*D_;
        const float* b2_i = b2   + (size_t)i * D_;

        // qkv = xb @ Wqkv^T + bqkv
        gemm_bf16<false><<<GM * (3*D_/128), 256, 0, stream>>>(
            xb, wq_i, bq_i, qkv_s, NTOK, 3*D_, D_);
        attn_kernel<<<dim3(NWIN, H_), 256, 0, stream>>>(qkv_s, ctx_s);
        // xb = LN1(xb + ctx @ Wo^T + bo)   (fused, in place)
        gemm_ln<<<NTOK/64, 512, 0, stream>>>(
            ctx_s, wo_i, bo_i, xb, xb,
            ln1g + (size_t)i*D_, ln1b + (size_t)i*D_, D_);
        // h = relu(xb @ W1^T + b1)
        gemm_bf16<true><<<GM * (4*D_/128), 256, 0, stream>>>(
            xb, w1_i, b1_i, h_s, NTOK, 4*D_, D_);
        // xb = LN2(xb + h @ W2^T + b2)     (fused, in place)
        gemm_ln<<<NTOK/64, 512, 0, stream>>>(
            h_s, w2_i, b2_i, xb, xb,
            ln2g + (size_t)i*D_, ln2b + (size_t)i*D_, 4*D_);
    }

    head_kernel<<<NWIN, 64, 0, stream>>>(xb, Wp, bp, Wv, bv, out);
}

// Round 10
// 4196.690 us; speedup vs baseline: 1.0969x; 1.0969x over previous
//
#include <hip/hip_runtime.h>
#include <hip/hip_bf16.h>
#include <cstdint>
#include <cstddef>

// Problem constants (fixed by reference)
#define B_    8
#define T_    256
#define D_    512
#define W_    32
#define L_    4
#define A_    6
#define H_    8
#define DH_   64
#define DHP   65                 // padded LDS row (attn bank-conflict fix, R5)
#define NWIN  (B_*T_)            // 2048 windows
#define NTOK  (NWIN*W_)          // 65536 token rows

typedef __hip_bfloat16 bf16;
using bf16x8 = __attribute__((ext_vector_type(8))) short;  // MFMA A/B frag (4 VGPR)
using f32x4  = __attribute__((ext_vector_type(4))) float;  // MFMA C/D frag

// ---- memory plan (bytes): bf16-only residual stream ----------------------
#define XB_BYTES  ((size_t)NTOK * D_ * 2)     // 64 MiB bf16 residual master
#define WQ_ELEMS  ((size_t)L_ * 3*D_*D_)
#define WO_ELEMS  ((size_t)L_ * D_*D_)
#define W1_ELEMS  ((size_t)L_ * 4*D_*D_)
#define W2_ELEMS  ((size_t)L_ * 4*D_*D_)
#define WB_BYTES  ((WQ_ELEMS + WO_ELEMS + W1_ELEMS + W2_ELEMS) * 2)
#define SCR_BYTES ((size_t)NTOK * 2048 * 2)   // qkv(1536)+ctx(512) / h(2048)
#define TOTAL_BYTES (XB_BYTES + WB_BYTES + SCR_BYTES)

static char* g_fallback = nullptr;
__attribute__((constructor)) static void alloc_fallback() {
    (void)hipMalloc((void**)&g_fallback, TOTAL_BYTES);
}

// ---- async global->LDS (16B per lane; LDS dest = wave base + lane*16) -----
typedef __attribute__((address_space(3))) uint8_t* as3p;
typedef const __attribute__((address_space(1))) uint8_t* as1p;
__device__ __forceinline__ void gload_lds16(const void* g, void* l) {
    __builtin_amdgcn_global_load_lds((as1p)(const uint8_t*)g,
                                     (as3p)(uint32_t)(uintptr_t)l, 16, 0, 0);
}

__device__ __forceinline__ float bf2f(short s) {
    return __uint_as_float(((uint32_t)(uint16_t)s) << 16);
}

// ---------------------------------------------------------------------------
// weight convert fp32 -> bf16 (4 elems/thread)
// ---------------------------------------------------------------------------
__global__ __launch_bounds__(256) void cvt_kernel(
    const float* __restrict__ w, bf16* __restrict__ o, int n4)
{
    int i = blockIdx.x * 256 + threadIdx.x;
    if (i >= n4) return;
    float4 f = ((const float4*)w)[i];
    bf16* d = o + (size_t)i * 4;
    d[0] = __float2bfloat16(f.x);
    d[1] = __float2bfloat16(f.y);
    d[2] = __float2bfloat16(f.z);
    d[3] = __float2bfloat16(f.w);
}

// ---------------------------------------------------------------------------
// build_x: xb[n*32+w,:] = bf16(feats[b, max(t+w-31,0),:] + pos[w,:])
// ---------------------------------------------------------------------------
__global__ __launch_bounds__(256) void build_x_kernel(
    const float* __restrict__ feats,
    const float* __restrict__ pos,
    bf16* __restrict__ xb)
{
    int gid   = blockIdx.x * 256 + threadIdx.x;   // over NTOK * (D/4)
    int token = gid >> 7;
    int c4    = (gid & 127) * 4;
    int w     = token & (W_-1);
    int n     = token >> 5;
    int t     = n & (T_-1);
    int b     = n >> 8;
    int frame = t + w - (W_-1); if (frame < 0) frame = 0;
    const float4 f = *(const float4*)(feats + ((size_t)(b*T_ + frame)*D_ + c4));
    const float4 p = *(const float4*)(pos   + ((size_t)w*D_ + c4));
    bf16* d = xb + (size_t)token*D_ + c4;
    d[0] = __float2bfloat16(f.x + p.x);
    d[1] = __float2bfloat16(f.y + p.y);
    d[2] = __float2bfloat16(f.z + p.z);
    d[3] = __float2bfloat16(f.w + p.w);
}

// ---------------------------------------------------------------------------
// bf16 MFMA GEMM (R8 version, BK=32 — R9's BK=64 regressed, cf m132):
// Cb = bf16(A(MxK) @ Bt(NxK)^T + bias [relu])
// 128x128 tile, 4 waves, wave 64x64 (4x4 of 16x16x32 MFMA).
// 1-D grid + XCD remap (R7: same-A-stripe blocks share one XCD L2).
// ---------------------------------------------------------------------------
template<bool RELU>
__global__ __launch_bounds__(256) void gemm_bf16(
    const bf16* __restrict__ A,
    const bf16* __restrict__ Bt,
    const float* __restrict__ bias,
    bf16* __restrict__ Cb,
    int M, int N, int K)
{
    __shared__ bf16 As[128*32];   // [row][k] row-major, 64B rows
    __shared__ bf16 Bs[128*32];

    const int tid  = threadIdx.x;
    const int lane = tid & 63;
    const int wv   = tid >> 6;

    // XCD-aware block remap (gridM % 8 == 0)
    const int gridN = N >> 7;
    const int bid   = blockIdx.x;
    const int q_    = bid >> 3;
    const int n0    = (q_ % gridN) << 7;
    const int m0    = (((q_ / gridN) * 8) + (bid & 7)) << 7;

    const int wm   = (wv >> 1) * 64;
    const int wn   = (wv & 1) * 64;

    f32x4 acc[4][4] = {};

    const int   srow  = wv*16 + (lane >> 2);
    const int   skoff = (lane & 3) * 8;
    const bf16* ga0 = A  + (size_t)(m0 + srow)      * K + skoff;
    const bf16* ga1 = A  + (size_t)(m0 + 64 + srow) * K + skoff;
    const bf16* gb0 = Bt + (size_t)(n0 + srow)      * K + skoff;
    const bf16* gb1 = Bt + (size_t)(n0 + 64 + srow) * K + skoff;
    char* lAs = (char*)As;
    char* lBs = (char*)Bs;
    const int l0 = wv*1024 + lane*16;

    const int fr = lane & 15;
    const int fq = (lane >> 4) * 16;

    for (int k0 = 0; k0 < K; k0 += 32) {
        gload_lds16(ga0 + k0, lAs + l0);
        gload_lds16(ga1 + k0, lAs + l0 + 4096);
        gload_lds16(gb0 + k0, lBs + l0);
        gload_lds16(gb1 + k0, lBs + l0 + 4096);
        __syncthreads();

        bf16x8 av[4], bv[4];
#pragma unroll
        for (int i = 0; i < 4; ++i) {
            av[i] = *(const bf16x8*)(lAs + (wm + i*16 + fr)*64 + fq);
            bv[i] = *(const bf16x8*)(lBs + (wn + i*16 + fr)*64 + fq);
        }
#pragma unroll
        for (int i = 0; i < 4; ++i)
#pragma unroll
            for (int j = 0; j < 4; ++j)
                acc[i][j] = __builtin_amdgcn_mfma_f32_16x16x32_bf16(
                    av[i], bv[j], acc[i][j], 0, 0, 0);
        __syncthreads();
    }

    // epilogue: C/D layout col=lane&15, row=(lane>>4)*4+reg
    const int er = (lane >> 4) * 4;
    const int ec = lane & 15;
#pragma unroll
    for (int i = 0; i < 4; ++i) {
#pragma unroll
        for (int j = 0; j < 4; ++j) {
            const int ncol = n0 + wn + j*16 + ec;
            const float bv_ = bias[ncol];
#pragma unroll
            for (int r = 0; r < 4; ++r) {
                const int mrow = m0 + wm + i*16 + er + r;
                float v = acc[i][j][r] + bv_;
                if (RELU) v = fmaxf(v, 0.f);
                Cb[(size_t)mrow * N + ncol] = __float2bfloat16(v);
            }
        }
    }
}

// ---------------------------------------------------------------------------
// Fused residual GEMM + LayerNorm (R8 32-row tile; R9 64-row was neutral):
//   y = xres + A @ Bt^T + bias;  xout = LN(y) * g + b      (N fixed = 512)
// Tile 32 rows x 512 cols per block -> block owns full rows, LN in-block.
// R10: block->row mapping REVERSED (m0 from grid top). A (h, 268 MB) is
// written by the producer immediately before this kernel; L3 = 256 MB, so
// the freshly-written TAIL of A is still L3-resident. Reading it first
// converts cold ~900-cyc HBM stalls into ~200-300-cyc cache hits (this
// kernel is latency-bound: R9 showed MfmaUtil 14%, VALU 9%, HBM 8%).
// In-place xres==xout safe: each block reads/writes only its own 32 rows.
// ---------------------------------------------------------------------------
__global__ __launch_bounds__(256) void gemm_ln(
    const bf16* __restrict__ A,     // (M x K)
    const bf16* __restrict__ Bt,    // (512 x K)
    const float* __restrict__ bias, // (512)
    const bf16* xres,               // (M x 512), aliases xout
    bf16* xout,
    const float* __restrict__ g,
    const float* __restrict__ b,
    int K)
{
    __shared__ bf16 As[32*32];      // 2 KB, 64B rows
    __shared__ bf16 Bs[512*32];     // 32 KB, 64B rows
    __shared__ float red[4][32][2]; // per-wave row partials

    const int tid  = threadIdx.x;
    const int lane = tid & 63;
    const int wv   = tid >> 6;
    const int m0   = (gridDim.x - 1 - blockIdx.x) * 32;   // reversed (L3 tail)

    f32x4 acc[2][8] = {};

    const bf16* gaA = A + (size_t)(m0 + (tid >> 2)) * K + (tid & 3) * 8; // tid<128
    const int   brow = wv*16 + (lane >> 2);
    const int   bkof = (lane & 3) * 8;
    char* lAs = (char*)As;
    char* lBs = (char*)Bs;
    const int l0 = wv*1024 + lane*16;

    const int fr = lane & 15;
    const int fq = (lane >> 4) * 16;
    const int wc = wv * 128;                      // wave col offset

    for (int k0 = 0; k0 < K; k0 += 32) {
        if (tid < 128) gload_lds16(gaA + k0, lAs + tid*16);
#pragma unroll
        for (int jj = 0; jj < 8; ++jj) {
            const bf16* gb = Bt + (size_t)(jj*64 + brow) * K + k0 + bkof;
            gload_lds16(gb, lBs + jj*4096 + l0);
        }
        __syncthreads();

        bf16x8 av[2], bv[8];
#pragma unroll
        for (int i = 0; i < 2; ++i)
            av[i] = *(const bf16x8*)(lAs + (i*16 + fr)*64 + fq);
#pragma unroll
        for (int j = 0; j < 8; ++j)
            bv[j] = *(const bf16x8*)(lBs + (wc + j*16 + fr)*64 + fq);
#pragma unroll
        for (int i = 0; i < 2; ++i)
#pragma unroll
            for (int j = 0; j < 8; ++j)
                acc[i][j] = __builtin_amdgcn_mfma_f32_16x16x32_bf16(
                    av[i], bv[j], acc[i][j], 0, 0, 0);
        __syncthreads();
    }

    // ---- epilogue: v = acc + bias + resid; LN over the 512-wide row ----
    const int er = (lane >> 4) * 4;
    const int ec = lane & 15;

    float bias_j[8];
#pragma unroll
    for (int j = 0; j < 8; ++j) bias_j[j] = bias[wc + j*16 + ec];

#pragma unroll
    for (int i = 0; i < 2; ++i) {
#pragma unroll
        for (int r = 0; r < 4; ++r) {
            const int row = i*16 + er + r;
            const bf16* xr = xres + (size_t)(m0 + row) * D_ + wc + ec;
            float s1 = 0.f, s2 = 0.f;
#pragma unroll
            for (int j = 0; j < 8; ++j) {
                float v = acc[i][j][r] + bias_j[j] + bf2f(*(const short*)(xr + j*16));
                acc[i][j][r] = v;
                s1 += v; s2 += v*v;
            }
#pragma unroll
            for (int mask = 1; mask < 16; mask <<= 1) {
                s1 += __shfl_xor(s1, mask, 64);
                s2 += __shfl_xor(s2, mask, 64);
            }
            if (ec == 0) { red[wv][row][0] = s1; red[wv][row][1] = s2; }
        }
    }
    __syncthreads();

#pragma unroll
    for (int i = 0; i < 2; ++i) {
#pragma unroll
        for (int r = 0; r < 4; ++r) {
            const int row = i*16 + er + r;
            float t1 = red[0][row][0] + red[1][row][0] + red[2][row][0] + red[3][row][0];
            float t2 = red[0][row][1] + red[1][row][1] + red[2][row][1] + red[3][row][1];
            const float mu  = t1 * (1.f / D_);
            float var = t2 * (1.f / D_) - mu * mu;
            if (var < 0.f) var = 0.f;
            const float rs = rsqrtf(var + 1e-5f);
            bf16* xo = xout + (size_t)(m0 + row) * D_ + wc + ec;
#pragma unroll
            for (int j = 0; j < 8; ++j) {
                const int col = wc + j*16 + ec;
                float o = (acc[i][j][r] - mu) * rs * g[col] + b[col];
                xo[j*16] = __float2bfloat16(o);
            }
        }
    }
}

// ---------------------------------------------------------------------------
// Attention: block per (window, head); bf16 qkv in, bf16 ctx out; fp32 inside.
// LDS rows padded to DHP=65 floats (R5 bank-conflict fix).
// ---------------------------------------------------------------------------
__global__ __launch_bounds__(256) void attn_kernel(
    const bf16* __restrict__ qkv,
    bf16* __restrict__ ctx)
{
    const int n = blockIdx.x;
    const int h = blockIdx.y;
    __shared__ float q[W_][DHP];
    __shared__ float k[W_][DHP];
    __shared__ float v[W_][DHP];
    __shared__ float s[W_][W_ + 1];

    const int tid = threadIdx.x;
    {
        int r  = tid >> 3;
        int c0 = (tid & 7) * 8;
        const bf16* base = qkv + (size_t)(n*W_ + r) * (3*D_) + h*DH_ + c0;
        bf16x8 tq = *(const bf16x8*)(base);
        bf16x8 tk = *(const bf16x8*)(base + D_);
        bf16x8 tv = *(const bf16x8*)(base + 2*D_);
#pragma unroll
        for (int j = 0; j < 8; ++j) {
            q[r][c0 + j] = bf2f(tq[j]);
            k[r][c0 + j] = bf2f(tk[j]);
            v[r][c0 + j] = bf2f(tv[j]);
        }
    }
    __syncthreads();

    const int i = tid >> 3;
    {
        int j0 = (tid & 7) * 4;
#pragma unroll
        for (int jj = 0; jj < 4; ++jj) {
            int j = j0 + jj;
            float d = 0.f;
#pragma unroll
            for (int kk = 0; kk < DH_; ++kk) d += q[i][kk] * k[j][kk];
            s[i][j] = (j <= i) ? d * 0.125f : -1e30f;
        }
    }
    __syncthreads();

    if (tid < W_) {
        float mx = -1e30f;
#pragma unroll
        for (int j = 0; j < W_; ++j) mx = fmaxf(mx, s[tid][j]);
        float sum = 0.f;
#pragma unroll
        for (int j = 0; j < W_; ++j) { float e = __expf(s[tid][j] - mx); s[tid][j] = e; sum += e; }
        float inv = 1.f / sum;
#pragma unroll
        for (int j = 0; j < W_; ++j) s[tid][j] *= inv;
    }
    __syncthreads();

    {
        int d0 = (tid & 7) * 8;
        float o[8] = {0,0,0,0,0,0,0,0};
#pragma unroll
        for (int j = 0; j < W_; ++j) {
            float a = s[i][j];
#pragma unroll
            for (int dd = 0; dd < 8; ++dd) o[dd] += a * v[j][d0 + dd];
        }
        bf16* dst = ctx + (size_t)(n*W_ + i) * D_ + h*DH_ + d0;
#pragma unroll
        for (int dd = 0; dd < 8; ++dd) dst[dd] = __float2bfloat16(o[dd]);
    }
}

// ---------------------------------------------------------------------------
// Head: token = xb[n*32+31,:] bf16; logits (NWIN,6) then values (NWIN)
// ---------------------------------------------------------------------------
__global__ __launch_bounds__(64) void head_kernel(
    const bf16* __restrict__ xb,
    const float* __restrict__ Wp, const float* __restrict__ bp,
    const float* __restrict__ Wv, const float* __restrict__ bv,
    float* __restrict__ out)
{
    const int n    = blockIdx.x;
    const int lane = threadIdx.x;
    const bf16* row = xb + (size_t)(n*W_ + (W_-1)) * D_;
    float t[8];
#pragma unroll
    for (int j = 0; j < 8; ++j) t[j] = bf2f(*(const short*)(row + lane + j*64));

    for (int a = 0; a < A_ + 1; ++a) {
        const float* w = (a < A_) ? (Wp + (size_t)a * D_) : Wv;
        float d = 0.f;
#pragma unroll
        for (int j = 0; j < 8; ++j) d += t[j] * w[lane + j*64];
#pragma unroll
        for (int off = 32; off > 0; off >>= 1) d += __shfl_down(d, off);
        if (lane == 0) {
            if (a < A_) out[(size_t)n*A_ + a] = d + bp[a];
            else        out[(size_t)NWIN*A_ + n] = d + bv[0];
        }
    }
}

// ---------------------------------------------------------------------------
extern "C" void kernel_launch(void* const* d_in, const int* in_sizes, int n_in,
                              void* d_out, int out_size, void* d_ws, size_t ws_size,
                              hipStream_t stream) {
    const float* feats = (const float*)d_in[0];
    const float* pos   = (const float*)d_in[1];
    const float* Wqkv  = (const float*)d_in[2];
    const float* bqkv  = (const float*)d_in[3];
    const float* Wo    = (const float*)d_in[4];
    const float* bo    = (const float*)d_in[5];
    const float* ln1g  = (const float*)d_in[6];
    const float* ln1b  = (const float*)d_in[7];
    const float* W1    = (const float*)d_in[8];
    const float* b1    = (const float*)d_in[9];
    const float* W2    = (const float*)d_in[10];
    const float* b2    = (const float*)d_in[11];
    const float* ln2g  = (const float*)d_in[12];
    const float* ln2b  = (const float*)d_in[13];
    const float* Wp    = (const float*)d_in[14];
    const float* bp    = (const float*)d_in[15];
    const float* Wv    = (const float*)d_in[16];
    const float* bv    = (const float*)d_in[17];
    float* out = (float*)d_out;

    char* basep = (ws_size >= TOTAL_BYTES) ? (char*)d_ws : g_fallback;

    bf16*  xb   = (bf16*)basep;
    bf16*  wq_b = (bf16*)(basep + XB_BYTES);
    bf16*  wo_b = wq_b + WQ_ELEMS;
    bf16*  w1_b = wo_b + WO_ELEMS;
    bf16*  w2_b = w1_b + W1_ELEMS;
    bf16*  scr  = w2_b + W2_ELEMS;
    bf16*  qkv_s = scr;                            // (NTOK, 1536)
    bf16*  ctx_s = scr + (size_t)NTOK * (3*D_);    // (NTOK, 512)
    bf16*  h_s   = scr;                            // (NTOK, 2048) FFN phase

    cvt_kernel<<<(WQ_ELEMS/4 + 255)/256, 256, 0, stream>>>(Wqkv, wq_b, WQ_ELEMS/4);
    cvt_kernel<<<(WO_ELEMS/4 + 255)/256, 256, 0, stream>>>(Wo,   wo_b, WO_ELEMS/4);
    cvt_kernel<<<(W1_ELEMS/4 + 255)/256, 256, 0, stream>>>(W1,   w1_b, W1_ELEMS/4);
    cvt_kernel<<<(W2_ELEMS/4 + 255)/256, 256, 0, stream>>>(W2,   w2_b, W2_ELEMS/4);

    build_x_kernel<<<NTOK * (D_/4) / 256, 256, 0, stream>>>(feats, pos, xb);

    const int GM = NTOK / 128;   // 512 m-blocks (div by 8, XCD remap ok)

    for (int i = 0; i < L_; ++i) {
        const bf16*  wq_i = wq_b + (size_t)i * 3*D_*D_;
        const float* bq_i = bqkv + (size_t)i * 3*D_;
        const bf16*  wo_i = wo_b + (size_t)i * D_*D_;
        const float* bo_i = bo   + (size_t)i * D_;
        const bf16*  w1_i = w1_b + (size_t)i * 4*D_*D_;
        const float* b1_i = b1   + (size_t)i * 4*D_;
        const bf16*  w2_i = w2_b + (size_t)i * 4*D_*D_;
        const float* b2_i = b2   + (size_t)i * D_;

        // qkv = xb @ Wqkv^T + bqkv
        gemm_bf16<false><<<GM * (3*D_/128), 256, 0, stream>>>(
            xb, wq_i, bq_i, qkv_s, NTOK, 3*D_, D_);
        attn_kernel<<<dim3(NWIN, H_), 256, 0, stream>>>(qkv_s, ctx_s);
        // xb = LN1(xb + ctx @ Wo^T + bo)   (fused, in place)
        gemm_ln<<<NTOK/32, 256, 0, stream>>>(
            ctx_s, wo_i, bo_i, xb, xb,
            ln1g + (size_t)i*D_, ln1b + (size_t)i*D_, D_);
        // h = relu(xb @ W1^T + b1)
        gemm_bf16<true><<<GM * (4*D_/128), 256, 0, stream>>>(
            xb, w1_i, b1_i, h_s, NTOK, 4*D_, D_);
        // xb = LN2(xb + h @ W2^T + b2)     (fused, in place)
        gemm_ln<<<NTOK/32, 256, 0, stream>>>(
            h_s, w2_i, b2_i, xb, xb,
            ln2g + (size_t)i*D_, ln2b + (size_t)i*D_, 4*D_);
    }

    head_kernel<<<NWIN, 64, 0, stream>>>(xb, Wp, bp, Wv, bv, out);
}